// Round 5
// baseline (413.246 us; speedup 1.0000x reference)
//
#include <hip/hip_runtime.h>

// CrossNet: B=500000 rows, D=128, L=4.
//   x0 = inputs; xl = x0
//   for i: s = dot(xl, w_i); xl = x0*s + b_i + xl
// Affine form: xl_i = alpha_i*x0 + beta_i, beta = cumsum(b) (row-independent),
//   alpha_{i+1} = alpha_i*(d_i+1) + c_i,  d_i = dot(x0,w_i), c_i = dot(beta_i,w_i).
// Out = alpha_L*x0 + beta_L.
//
// Round-5 change (ONLY): grid 4096 -> 2048. 4096 blocks = 16384 waves > the
// 8192-wave machine capacity, so the dispatch ran as TWO sequential block
// generations: two latency ramps, two weight preloads, double tail -- matching
// the observed 72% average occupancy. 2048 blocks = exactly 8 blocks/CU =
// 32 waves/CU, one resident generation, ~15 grid-stride iterations per wave.
// Compute structure identical to round 4 (16-lane DPP reduce, 1-deep
// prefetch, nontemporal loads+stores).

#define CN_D 128
#define CN_L 4

typedef float fvec4 __attribute__((ext_vector_type(4)));

// 16-lane all-reduce, pure VALU (DPP). quad_perm [1,0,3,2]=0xB1 (xor1),
// [2,3,0,1]=0x4E (xor2), row_ror:4=0x124, row_ror:8=0x128.
template <int CTRL>
__device__ __forceinline__ float dpp_radd(float x) {
    int t = __builtin_amdgcn_update_dpp(0, __float_as_int(x), CTRL, 0xF, 0xF, true);
    return x + __int_as_float(t);
}
__device__ __forceinline__ float row16_allreduce(float x) {
    x = dpp_radd<0xB1>(x);   // + lane^1
    x = dpp_radd<0x4E>(x);   // + lane^2  -> quad sums
    x = dpp_radd<0x124>(x);  // + rot4    -> 2-quad sums
    x = dpp_radd<0x128>(x);  // + rot8    -> full 16-lane sum, all lanes
    return x;
}

__global__ __launch_bounds__(256) void crossnet_kernel(
    const float* __restrict__ inputs,
    const float* __restrict__ kernels,
    const float* __restrict__ biases,
    float* __restrict__ out,
    int nrows)
{
    const int lane = threadIdx.x & 15;   // float4 chunk index (lo half)
    const int grp  = threadIdx.x >> 4;   // 0..15 rows per block
    const int gpb  = blockDim.x >> 4;    // 16 rows per block per iter

    // Per-lane weight fragments (L2-resident broadcast; normal loads).
    float4 wlo[CN_L], whi[CN_L];
#pragma unroll
    for (int i = 0; i < CN_L; ++i) {
        wlo[i] = ((const float4*)(kernels + i * CN_D))[lane];
        whi[i] = ((const float4*)(kernels + i * CN_D))[lane + 16];
    }

    // beta_L fragments and c[i] = dot(beta_i, w_i).
    float c[CN_L];
    float4 blo = make_float4(0.f, 0.f, 0.f, 0.f);
    float4 bhi = make_float4(0.f, 0.f, 0.f, 0.f);
#pragma unroll
    for (int i = 0; i < CN_L; ++i) {
        float p = blo.x*wlo[i].x + blo.y*wlo[i].y + blo.z*wlo[i].z + blo.w*wlo[i].w
                + bhi.x*whi[i].x + bhi.y*whi[i].y + bhi.z*whi[i].z + bhi.w*whi[i].w;
        c[i] = row16_allreduce(p);
        float4 t;
        t = ((const float4*)(biases + i * CN_D))[lane];
        blo.x += t.x; blo.y += t.y; blo.z += t.z; blo.w += t.w;
        t = ((const float4*)(biases + i * CN_D))[lane + 16];
        bhi.x += t.x; bhi.y += t.y; bhi.z += t.z; bhi.w += t.w;
    }

    const int stride = gridDim.x * gpb;       // total row-slots per sweep
    int row = blockIdx.x * gpb + grp;
    if (row >= nrows) return;                 // no barriers: safe

    const fvec4* __restrict__ in4  = (const fvec4*)inputs;
    fvec4* __restrict__       out4 = (fvec4*)out;

    // Prime the pipeline (nontemporal: single-touch stream, don't allocate).
    fvec4 xlo = __builtin_nontemporal_load(in4 + row * 32 + lane);
    fvec4 xhi = __builtin_nontemporal_load(in4 + row * 32 + lane + 16);

    while (true) {
        // ---- prefetch next row while we reduce the current one ----
        const int rnext = row + stride;
        const bool hasN = rnext < nrows;
        const int rn = hasN ? rnext : row;    // clamp keeps the load legal
        fvec4 nlo = __builtin_nontemporal_load(in4 + rn * 32 + lane);
        fvec4 nhi = __builtin_nontemporal_load(in4 + rn * 32 + lane + 16);

        // ---- 4 independent per-lane dot partials (8 elems each) ----
        float d0, d1, d2, d3;
        d0 = xlo.x * wlo[0].x;                 d1 = xlo.x * wlo[1].x;
        d2 = xlo.x * wlo[2].x;                 d3 = xlo.x * wlo[3].x;
        d0 = fmaf(xlo.y, wlo[0].y, d0);        d1 = fmaf(xlo.y, wlo[1].y, d1);
        d2 = fmaf(xlo.y, wlo[2].y, d2);        d3 = fmaf(xlo.y, wlo[3].y, d3);
        d0 = fmaf(xlo.z, wlo[0].z, d0);        d1 = fmaf(xlo.z, wlo[1].z, d1);
        d2 = fmaf(xlo.z, wlo[2].z, d2);        d3 = fmaf(xlo.z, wlo[3].z, d3);
        d0 = fmaf(xlo.w, wlo[0].w, d0);        d1 = fmaf(xlo.w, wlo[1].w, d1);
        d2 = fmaf(xlo.w, wlo[2].w, d2);        d3 = fmaf(xlo.w, wlo[3].w, d3);
        d0 = fmaf(xhi.x, whi[0].x, d0);        d1 = fmaf(xhi.x, whi[1].x, d1);
        d2 = fmaf(xhi.x, whi[2].x, d2);        d3 = fmaf(xhi.x, whi[3].x, d3);
        d0 = fmaf(xhi.y, whi[0].y, d0);        d1 = fmaf(xhi.y, whi[1].y, d1);
        d2 = fmaf(xhi.y, whi[2].y, d2);        d3 = fmaf(xhi.y, whi[3].y, d3);
        d0 = fmaf(xhi.z, whi[0].z, d0);        d1 = fmaf(xhi.z, whi[1].z, d1);
        d2 = fmaf(xhi.z, whi[2].z, d2);        d3 = fmaf(xhi.z, whi[3].z, d3);
        d0 = fmaf(xhi.w, whi[0].w, d0);        d1 = fmaf(xhi.w, whi[1].w, d1);
        d2 = fmaf(xhi.w, whi[2].w, d2);        d3 = fmaf(xhi.w, whi[3].w, d3);

        // ---- pure-VALU reductions (4 independent DPP chains) ----
        d0 = row16_allreduce(d0);
        d1 = row16_allreduce(d1);
        d2 = row16_allreduce(d2);
        d3 = row16_allreduce(d3);

        // ---- alpha recurrence ----
        float a = d0 + 1.f + c[0];
        a = fmaf(a, d1 + 1.f, c[1]);
        a = fmaf(a, d2 + 1.f, c[2]);
        a = fmaf(a, d3 + 1.f, c[3]);

        // ---- out = alpha*x0 + beta (nontemporal store) ----
        fvec4 olo, ohi;
        olo.x = fmaf(a, xlo.x, blo.x);  olo.y = fmaf(a, xlo.y, blo.y);
        olo.z = fmaf(a, xlo.z, blo.z);  olo.w = fmaf(a, xlo.w, blo.w);
        ohi.x = fmaf(a, xhi.x, bhi.x);  ohi.y = fmaf(a, xhi.y, bhi.y);
        ohi.z = fmaf(a, xhi.z, bhi.z);  ohi.w = fmaf(a, xhi.w, bhi.w);

        __builtin_nontemporal_store(olo, out4 + row * 32 + lane);
        __builtin_nontemporal_store(ohi, out4 + row * 32 + lane + 16);

        if (!hasN) break;
        row = rnext;
        xlo = nlo;
        xhi = nhi;
    }
}

extern "C" void kernel_launch(void* const* d_in, const int* in_sizes, int n_in,
                              void* d_out, int out_size, void* d_ws, size_t ws_size,
                              hipStream_t stream) {
    const float* inputs  = (const float*)d_in[0];
    const float* kernels = (const float*)d_in[1];
    const float* biases  = (const float*)d_in[2];
    float* out = (float*)d_out;

    const int nrows = in_sizes[0] / CN_D;  // 500000

    // 2048 blocks = 8 blocks/CU x 256 CU = 32 waves/CU: exactly one resident
    // generation (4096 ran as two sequential generations -> 72% avg occupancy).
    const int block = 256;                 // 16 rows per block per iteration
    const int grid  = 2048;                // 32768 row-slots; ~15 iters each

    crossnet_kernel<<<grid, block, 0, stream>>>(inputs, kernels, biases, out, nrows);
}